// Round 15
// baseline (213.583 us; speedup 1.0000x reference)
//
#include <hip/hip_runtime.h>
#include <hip/hip_bf16.h>
#include <hip/hip_fp16.h>

// GCN round 15: conv blocks 512->256 thr (4 waves x 4 nodes; 8 blocks/CU so
// the 625-block grid tail smooths at full 32-wave occupancy). Scan folded
// into enc_hist via last-block pattern (device-scope fence + atomic reads).
// 6 launches: prep, enc+hist(+scan), passB(claim), conv1, conv2, conv3+dec.

#define NNODES 10000
#define NEDGES 640000
#define HDIM   128
#define CDIM   64
#define NLAYER 3
#define NB     200
#define CHUNK  (NEDGES / NB)
#define ENCB   157               // encoder blocks in fused kernel

typedef _Float16 half8 __attribute__((ext_vector_type(8)));
typedef float    f32x4 __attribute__((ext_vector_type(4)));

// ---------------- prep: weights -> transposed fp16 [n][k]; zero total/done ----------------
__global__ __launch_bounds__(256) void prep_kernel(
    const float* __restrict__ enc_W,
    const float* __restrict__ conv_W,
    const float* __restrict__ dec_W,
    _Float16* __restrict__ wt_all,     // enc[16384] conv[3*16384] dec[8192]
    int* __restrict__ total,
    int* __restrict__ done)
{
    const int b = blockIdx.x, t = threadIdx.x;
    if (b == 5) {
        for (int i = t; i < NNODES; i += 256) total[i] = 0;
        if (t == 0) *done = 0;
        return;
    }
    const float* W; _Float16* Wt; int NC, tot;
    if (b == 0)      { W = enc_W;                  Wt = wt_all;             NC = 128; tot = 16384; }
    else if (b <= 3) { W = conv_W + (b - 1) * 16384; Wt = wt_all + b * 16384; NC = 128; tot = 16384; }
    else             { W = dec_W;                  Wt = wt_all + 4 * 16384; NC = 64;  tot = 8192; }
    for (int idx = t; idx < tot; idx += 256) {
        int n = idx >> 7, k = idx & 127;
        Wt[idx] = (_Float16)W[k * NC + n];
    }
}

// ---- encoder tile (16 rows), executed by a 256-thread subgroup ----
__device__ __forceinline__ void enc_tile(int tile, int tid,
    const float* __restrict__ A, const _Float16* __restrict__ Wt,
    const float* __restrict__ bias, _Float16* __restrict__ outv)
{
    const int wave = tid >> 6;
    const int lane = tid & 63;
    const int base = tile * 16;
    const int m  = lane & 15;
    const int kg = lane >> 4;
    const int row = base + m;

    f32x4 acc[2];
    acc[0] = (f32x4){0.f, 0.f, 0.f, 0.f};
    acc[1] = (f32x4){0.f, 0.f, 0.f, 0.f};

    #pragma unroll
    for (int ks = 0; ks < 4; ++ks) {
        half8 a;
        const float* ap = A + (size_t)row * 128 + kg * 8 + ks * 32;
        float4 u0 = *(const float4*)(ap);
        float4 u1 = *(const float4*)(ap + 4);
        a[0] = (_Float16)u0.x; a[1] = (_Float16)u0.y;
        a[2] = (_Float16)u0.z; a[3] = (_Float16)u0.w;
        a[4] = (_Float16)u1.x; a[5] = (_Float16)u1.y;
        a[6] = (_Float16)u1.z; a[7] = (_Float16)u1.w;
        #pragma unroll
        for (int q = 0; q < 2; ++q) {
            const int nt = wave + q * 4;
            half8 b = *(const half8*)(Wt + (size_t)(nt * 16 + m) * 128 + ks * 32 + kg * 8);
            acc[q] = __builtin_amdgcn_mfma_f32_16x16x32_f16(a, b, acc[q], 0, 0, 0);
        }
    }

    #pragma unroll
    for (int q = 0; q < 2; ++q) {
        const int col = (wave + q * 4) * 16 + m;
        float bv = bias[col];
        #pragma unroll
        for (int r = 0; r < 4; ++r) {
            int orow = base + kg * 4 + r;
            outv[(size_t)orow * 128 + col] = (_Float16)tanhf(acc[q][r] + bv);
        }
    }
}

// ---------------- fused: hist + encoder + last-block scan ----------------
__global__ __launch_bounds__(1024) void enc_hist_kernel(
    const int* __restrict__ dst,
    unsigned short* __restrict__ counts,
    int* __restrict__ total,
    int* __restrict__ done,
    int* __restrict__ rs,
    int* __restrict__ cur,
    const float* __restrict__ x,
    const _Float16* __restrict__ encWt,
    const float* __restrict__ enc_b,
    _Float16* __restrict__ h)
{
    __shared__ int hist[NNODES];
    __shared__ int part[1024];
    __shared__ int lastflag;
    const int b = blockIdx.x, t = threadIdx.x;

    if (b >= NB) {
        int tile = (b - NB) * 4 + (t >> 8);
        if (tile < NNODES / 16)
            enc_tile(tile, t & 255, x, encWt, enc_b, h);
        return;
    }

    for (int i = t; i < NNODES; i += 1024) hist[i] = 0;
    __syncthreads();
    const int e0 = b * CHUNK, e1 = e0 + CHUNK;
    for (int e = e0 + t; e < e1; e += 1024) atomicAdd(&hist[dst[e]], 1);
    __syncthreads();
    for (int i = t; i < NNODES; i += 1024) {
        int c = hist[i];
        counts[b * NNODES + i] = (unsigned short)c;
        if (c) atomicAdd(&total[i], c);
    }

    // last hist block performs the scan
    __threadfence();
    __syncthreads();
    if (t == 0) {
        int prev = atomicAdd(done, 1);
        lastflag = (prev == NB - 1);
    }
    __syncthreads();
    if (!lastflag) return;

    // scan total -> rs, cur (device-scope atomic loads: bypass stale L1/L2)
    const int per = (NNODES + 1023) / 1024;
    const int begin = t * per;
    int loc[10];
    int s = 0;
    for (int j = 0; j < per; ++j) {
        int i = begin + j;
        int v = (i < NNODES)
              ? __hip_atomic_load(&total[i], __ATOMIC_RELAXED, __HIP_MEMORY_SCOPE_AGENT)
              : 0;
        loc[j] = v;
        s += v;
    }
    part[t] = s;
    __syncthreads();
    for (int off = 1; off < 1024; off <<= 1) {
        int v = (t >= off) ? part[t - off] : 0;
        __syncthreads();
        part[t] += v;
        __syncthreads();
    }
    int excl = part[t] - s;
    for (int j = 0; j < per; ++j) {
        int i = begin + j;
        if (i < NNODES) {
            rs[i]  = excl;
            cur[i] = excl;
            excl += loc[j];
        }
    }
    if (t == 1023) rs[NNODES] = NEDGES;
}

// ---------------- passB: load counts row, claim ranges, LDS-cursor scatter ----------------
__global__ __launch_bounds__(1024) void passB_claim(const int* __restrict__ src,
                                                    const int* __restrict__ dst,
                                                    const float* __restrict__ ew,
                                                    const unsigned short* __restrict__ counts,
                                                    int* __restrict__ cur,
                                                    unsigned int* __restrict__ csr)
{
    __shared__ int hist[NNODES];
    const int b = blockIdx.x, t = threadIdx.x;
    for (int i = t; i < NNODES; i += 1024) {
        int c = counts[b * NNODES + i];
        hist[i] = c ? atomicAdd(&cur[i], c) : 0;
    }
    __syncthreads();
    const int e0 = b * CHUNK, e1 = e0 + CHUNK;
    for (int e = e0 + t; e < e1; e += 1024) {
        int d = dst[e];
        int p = atomicAdd(&hist[d], 1);
        unsigned int pk = (unsigned int)src[e]
                        | ((unsigned int)__half_as_ushort(__float2half_rn(ew[e])) << 16);
        csr[p] = pk;
    }
}

// ---------------- fused conv layer: 256 thr, 4 waves x 4 nodes ----------------
#define EDGE_ACC(pk, vv)                                                 \
    do {                                                                 \
        __half wh; *(unsigned short*)&wh = (unsigned short)((pk) >> 16); \
        float w = __half2float(wh);                                      \
        half8 hv = *(const half8*)&(vv);                                 \
        _Pragma("unroll")                                                \
        for (int j = 0; j < 8; ++j)                                      \
            acc[j] = fmaf((float)hv[j], w, acc[j]);                      \
    } while (0)

template<bool DEC>
__global__ __launch_bounds__(256, 8) void conv_fused(
    const unsigned char* __restrict__ hinB,  // [N][256] bytes (fp16 rows)
    const int* __restrict__ rs,              // [N+1]
    const unsigned int* __restrict__ csr,    // [E] packed (src | f16w<<16)
    const _Float16* __restrict__ Wt,         // [128,128] fp16 n-major
    const float* __restrict__ bias,          // [128] fp32
    _Float16* __restrict__ hout,             // [N,128] fp16 (unused if DEC)
    const _Float16* __restrict__ decWt,      // [64,128] fp16 n-major (DEC only)
    const float* __restrict__ dec_b,         // [64] (DEC only)
    float* __restrict__ decout)              // [N,64] fp32 (DEC only)
{
    __shared__ _Float16 Alds[16][136];

    const int t    = threadIdx.x;
    const int wv   = __builtin_amdgcn_readfirstlane(t >> 6);   // 0..3
    const int lane = t & 63;
    const int grp  = lane >> 4;
    const int li   = lane & 15;
    const int base = blockIdx.x * 16;

    for (int i = 0; i < 4; ++i) {
        const int r   = wv * 4 + i;
        const int wid = base + r;
        const int e0  = rs[wid];
        const int e1  = rs[wid + 1];

        float acc[8];
        #pragma unroll
        for (int q = 0; q < 8; ++q) acc[q] = 0.f;

        for (int sb = e0; sb < e1; sb += 64) {
            const int nrem = min(64, e1 - sb);
            unsigned int vp = csr[sb + (lane < nrem ? lane : 0)];
            const int nfg = nrem >> 2;
            int g = 0;
            for (; g + 4 <= nfg; g += 4) {
                unsigned int ps[4]; uint4 v[4];
                #pragma unroll
                for (int q = 0; q < 4; ++q) ps[q] = __shfl(vp, 4 * (g + q) + grp, 64);
                #pragma unroll
                for (int q = 0; q < 4; ++q)
                    v[q] = *(const uint4*)(hinB + ((ps[q] & 0x3FFFu) << 8) + (li << 4));
                #pragma unroll
                for (int q = 0; q < 4; ++q) EDGE_ACC(ps[q], v[q]);
            }
            for (; g < nfg; ++g) {
                unsigned int ps = __shfl(vp, 4 * g + grp, 64);
                uint4 v = *(const uint4*)(hinB + ((ps & 0x3FFFu) << 8) + (li << 4));
                EDGE_ACC(ps, v);
            }
            if (nrem & 3) {
                unsigned int ps = __shfl(vp, 4 * g + grp, 64);
                if (4 * g + grp >= nrem) ps &= 0x3FFFu;   // weight := +0.0
                uint4 v = *(const uint4*)(hinB + ((ps & 0x3FFFu) << 8) + (li << 4));
                EDGE_ACC(ps, v);
            }
        }

        #pragma unroll
        for (int q = 0; q < 8; ++q) {
            float s = acc[q];
            s += __shfl_xor(s, 16, 64);
            s += __shfl_xor(s, 32, 64);
            acc[q] = s;
        }

        if (grp == 0) {
            _Float16 hv[8];
            #pragma unroll
            for (int q = 0; q < 8; ++q) hv[q] = (_Float16)acc[q];
            *(uint4*)(&Alds[r][li * 8]) = *(uint4*)hv;
        }
    }
    __syncthreads();

    // MFMA: wave wv computes col-tiles wv and wv+4
    const int m  = li;
    const int kg = grp;
    float tv[2][4];
    #pragma unroll
    for (int q = 0; q < 2; ++q) {
        const int ct = wv + q * 4;
        f32x4 macc = (f32x4){0.f, 0.f, 0.f, 0.f};
        #pragma unroll
        for (int ks = 0; ks < 4; ++ks) {
            half8 a  = *(const half8*)(&Alds[m][kg * 8 + ks * 32]);
            half8 bb = *(const half8*)(Wt + (size_t)(ct * 16 + m) * 128 + ks * 32 + kg * 8);
            macc = __builtin_amdgcn_mfma_f32_16x16x32_f16(a, bb, macc, 0, 0, 0);
        }
        const float bv = bias[ct * 16 + m];
        #pragma unroll
        for (int r = 0; r < 4; ++r) tv[q][r] = tanhf(macc[r] + bv);
    }

    if (!DEC) {
        #pragma unroll
        for (int q = 0; q < 2; ++q) {
            const int col = (wv + q * 4) * 16 + m;
            #pragma unroll
            for (int r = 0; r < 4; ++r)
                hout[(size_t)(base + kg * 4 + r) * 128 + col] = (_Float16)tv[q][r];
        }
    } else {
        __syncthreads();   // all Alds reads done; reuse tile for tanh'd h
        #pragma unroll
        for (int q = 0; q < 2; ++q) {
            const int col = (wv + q * 4) * 16 + m;
            #pragma unroll
            for (int r = 0; r < 4; ++r) Alds[kg * 4 + r][col] = (_Float16)tv[q][r];
        }
        __syncthreads();
        // decoder: 64 cols, wave wv does col-tile wv
        f32x4 dacc = (f32x4){0.f, 0.f, 0.f, 0.f};
        #pragma unroll
        for (int ks = 0; ks < 4; ++ks) {
            half8 a  = *(const half8*)(&Alds[m][kg * 8 + ks * 32]);
            half8 bb = *(const half8*)(decWt + (size_t)(wv * 16 + m) * 128 + ks * 32 + kg * 8);
            dacc = __builtin_amdgcn_mfma_f32_16x16x32_f16(a, bb, dacc, 0, 0, 0);
        }
        const float dbv = dec_b[wv * 16 + m];
        #pragma unroll
        for (int r = 0; r < 4; ++r)
            decout[(size_t)(base + kg * 4 + r) * 64 + wv * 16 + m] = dacc[r] + dbv;
    }
}

// ---------------- launch ----------------
extern "C" void kernel_launch(void* const* d_in, const int* in_sizes, int n_in,
                              void* d_out, int out_size, void* d_ws, size_t ws_size,
                              hipStream_t stream)
{
    const float* x      = (const float*)d_in[0];
    const int*   ei     = (const int*)  d_in[1];
    const float* ew     = (const float*)d_in[2];
    const float* enc_W  = (const float*)d_in[3];
    const float* enc_b  = (const float*)d_in[4];
    const float* conv_W = (const float*)d_in[5];
    const float* conv_b = (const float*)d_in[6];
    const float* dec_W  = (const float*)d_in[7];
    const float* dec_b  = (const float*)d_in[8];
    float* out = (float*)d_out;

    const int N = NNODES, E = NEDGES, H = HDIM;

    // workspace layout
    _Float16*       h      = (_Float16*)d_ws;                     // [N,128]  2.56MB
    _Float16*       h2     = h + (size_t)N * H;                   // [N,128]  2.56MB
    _Float16*       wt_all = h2 + (size_t)N * H;                  // 81920    160KB
    unsigned int*   csr    = (unsigned int*)(wt_all + 5 * 16384); // [E]      2.56MB
    unsigned short* counts = (unsigned short*)(csr + E);          // [NB][N]  4MB
    int*            total  = (int*)(counts + (size_t)NB * N);     // [N]
    int*            rs     = total + N;                           // [N+1]
    int*            cur    = rs + (N + 1);                        // [N]
    int*            done   = cur + N;                             // [1]

    const int* src = ei;
    const int* dst = ei + E;

    prep_kernel<<<6, 256, 0, stream>>>(enc_W, conv_W, dec_W, wt_all, total, done);

    // fused: hist (200 blocks) + encoder (157 blocks) + last-block scan
    enc_hist_kernel<<<NB + ENCB, 1024, 0, stream>>>(dst, counts, total, done, rs, cur,
                                                    x, wt_all, enc_b, h);

    passB_claim<<<NB, 1024, 0, stream>>>(src, dst, ew, counts, cur, csr);

    // conv layers (linearity reorder): h_{l+1} = tanh((sum w*h_l[src]) @ W_l + b_l)
    conv_fused<false><<<N / 16, 256, 0, stream>>>((const unsigned char*)h, rs, csr,
                                                  wt_all + 1 * 16384, conv_b + 0 * H,
                                                  h2, nullptr, nullptr, nullptr);
    conv_fused<false><<<N / 16, 256, 0, stream>>>((const unsigned char*)h2, rs, csr,
                                                  wt_all + 2 * 16384, conv_b + 1 * H,
                                                  h, nullptr, nullptr, nullptr);
    conv_fused<true><<<N / 16, 256, 0, stream>>>((const unsigned char*)h, rs, csr,
                                                 wt_all + 3 * 16384, conv_b + 2 * H,
                                                 h2, wt_all + 4 * 16384, dec_b, out);
}

// Round 16
// 129.036 us; speedup vs baseline: 1.6552x; 1.6552x over previous
//
#include <hip/hip_runtime.h>
#include <hip/hip_bf16.h>
#include <hip/hip_fp16.h>

// GCN round 16: R14 structure (separate 1-block scan — last-block fence
// pattern cost ~100us, reverted) + 256-thr conv blocks (4 waves x 4 nodes,
// 8 blocks/CU). 7 launches: prep, enc+hist, scan, passB, conv1, conv2, conv3+dec.

#define NNODES 10000
#define NEDGES 640000
#define HDIM   128
#define CDIM   64
#define NLAYER 3
#define NB     200
#define CHUNK  (NEDGES / NB)
#define ENCB   157               // encoder blocks in fused kernel

typedef _Float16 half8 __attribute__((ext_vector_type(8)));
typedef float    f32x4 __attribute__((ext_vector_type(4)));

// ---------------- prep: weights -> transposed fp16 [n][k]; zero total ----------------
__global__ __launch_bounds__(256) void prep_kernel(
    const float* __restrict__ enc_W,
    const float* __restrict__ conv_W,
    const float* __restrict__ dec_W,
    _Float16* __restrict__ wt_all,     // enc[16384] conv[3*16384] dec[8192]
    int* __restrict__ total)
{
    const int b = blockIdx.x, t = threadIdx.x;
    if (b == 5) {
        for (int i = t; i < NNODES; i += 256) total[i] = 0;
        return;
    }
    const float* W; _Float16* Wt; int NC, tot;
    if (b == 0)      { W = enc_W;                  Wt = wt_all;             NC = 128; tot = 16384; }
    else if (b <= 3) { W = conv_W + (b - 1) * 16384; Wt = wt_all + b * 16384; NC = 128; tot = 16384; }
    else             { W = dec_W;                  Wt = wt_all + 4 * 16384; NC = 64;  tot = 8192; }
    for (int idx = t; idx < tot; idx += 256) {
        int n = idx >> 7, k = idx & 127;
        Wt[idx] = (_Float16)W[k * NC + n];
    }
}

// ---- encoder tile (16 rows), executed by a 256-thread subgroup ----
__device__ __forceinline__ void enc_tile(int tile, int tid,
    const float* __restrict__ A, const _Float16* __restrict__ Wt,
    const float* __restrict__ bias, _Float16* __restrict__ outv)
{
    const int wave = tid >> 6;
    const int lane = tid & 63;
    const int base = tile * 16;
    const int m  = lane & 15;
    const int kg = lane >> 4;
    const int row = base + m;

    f32x4 acc[2];
    acc[0] = (f32x4){0.f, 0.f, 0.f, 0.f};
    acc[1] = (f32x4){0.f, 0.f, 0.f, 0.f};

    #pragma unroll
    for (int ks = 0; ks < 4; ++ks) {
        half8 a;
        const float* ap = A + (size_t)row * 128 + kg * 8 + ks * 32;
        float4 u0 = *(const float4*)(ap);
        float4 u1 = *(const float4*)(ap + 4);
        a[0] = (_Float16)u0.x; a[1] = (_Float16)u0.y;
        a[2] = (_Float16)u0.z; a[3] = (_Float16)u0.w;
        a[4] = (_Float16)u1.x; a[5] = (_Float16)u1.y;
        a[6] = (_Float16)u1.z; a[7] = (_Float16)u1.w;
        #pragma unroll
        for (int q = 0; q < 2; ++q) {
            const int nt = wave + q * 4;
            half8 b = *(const half8*)(Wt + (size_t)(nt * 16 + m) * 128 + ks * 32 + kg * 8);
            acc[q] = __builtin_amdgcn_mfma_f32_16x16x32_f16(a, b, acc[q], 0, 0, 0);
        }
    }

    #pragma unroll
    for (int q = 0; q < 2; ++q) {
        const int col = (wave + q * 4) * 16 + m;
        float bv = bias[col];
        #pragma unroll
        for (int r = 0; r < 4; ++r) {
            int orow = base + kg * 4 + r;
            outv[(size_t)orow * 128 + col] = (_Float16)tanhf(acc[q][r] + bv);
        }
    }
}

// ---------------- fused: hist (blocks 0..NB-1) + encoder (blocks NB..) ----------------
__global__ __launch_bounds__(1024) void enc_hist_kernel(
    const int* __restrict__ dst,
    unsigned short* __restrict__ counts,
    int* __restrict__ total,
    const float* __restrict__ x,
    const _Float16* __restrict__ encWt,
    const float* __restrict__ enc_b,
    _Float16* __restrict__ h)
{
    __shared__ int hist[NNODES];
    const int b = blockIdx.x, t = threadIdx.x;

    if (b >= NB) {
        int tile = (b - NB) * 4 + (t >> 8);
        if (tile < NNODES / 16)
            enc_tile(tile, t & 255, x, encWt, enc_b, h);
        return;
    }

    for (int i = t; i < NNODES; i += 1024) hist[i] = 0;
    __syncthreads();
    const int e0 = b * CHUNK, e1 = e0 + CHUNK;
    for (int e = e0 + t; e < e1; e += 1024) atomicAdd(&hist[dst[e]], 1);
    __syncthreads();
    for (int i = t; i < NNODES; i += 1024) {
        int c = hist[i];
        counts[b * NNODES + i] = (unsigned short)c;
        if (c) atomicAdd(&total[i], c);
    }
}

// ---------------- scan: rs = exclusive_scan(total); cur = rs ----------------
__global__ __launch_bounds__(1024) void scan_kernel(const int* __restrict__ total,
                                                    int* __restrict__ rs,
                                                    int* __restrict__ cur)
{
    __shared__ int part[1024];
    const int t = threadIdx.x;
    const int per = (NNODES + 1023) / 1024;
    const int begin = t * per;
    int s = 0;
    for (int j = 0; j < per; ++j) {
        int i = begin + j;
        if (i < NNODES) s += total[i];
    }
    part[t] = s;
    __syncthreads();
    for (int off = 1; off < 1024; off <<= 1) {
        int v = (t >= off) ? part[t - off] : 0;
        __syncthreads();
        part[t] += v;
        __syncthreads();
    }
    int excl = part[t] - s;
    for (int j = 0; j < per; ++j) {
        int i = begin + j;
        if (i < NNODES) {
            rs[i]  = excl;
            cur[i] = excl;
            excl += total[i];
        }
    }
    if (t == 1023) rs[NNODES] = part[1023];
}

// ---------------- passB: load counts row, claim ranges, LDS-cursor scatter ----------------
__global__ __launch_bounds__(1024) void passB_claim(const int* __restrict__ src,
                                                    const int* __restrict__ dst,
                                                    const float* __restrict__ ew,
                                                    const unsigned short* __restrict__ counts,
                                                    int* __restrict__ cur,
                                                    unsigned int* __restrict__ csr)
{
    __shared__ int hist[NNODES];
    const int b = blockIdx.x, t = threadIdx.x;
    for (int i = t; i < NNODES; i += 1024) {
        int c = counts[b * NNODES + i];
        hist[i] = c ? atomicAdd(&cur[i], c) : 0;
    }
    __syncthreads();
    const int e0 = b * CHUNK, e1 = e0 + CHUNK;
    for (int e = e0 + t; e < e1; e += 1024) {
        int d = dst[e];
        int p = atomicAdd(&hist[d], 1);
        unsigned int pk = (unsigned int)src[e]
                        | ((unsigned int)__half_as_ushort(__float2half_rn(ew[e])) << 16);
        csr[p] = pk;
    }
}

// ---------------- fused conv layer: 256 thr, 4 waves x 4 nodes ----------------
#define EDGE_ACC(pk, vv)                                                 \
    do {                                                                 \
        __half wh; *(unsigned short*)&wh = (unsigned short)((pk) >> 16); \
        float w = __half2float(wh);                                      \
        half8 hv = *(const half8*)&(vv);                                 \
        _Pragma("unroll")                                                \
        for (int j = 0; j < 8; ++j)                                      \
            acc[j] = fmaf((float)hv[j], w, acc[j]);                      \
    } while (0)

template<bool DEC>
__global__ __launch_bounds__(256, 8) void conv_fused(
    const unsigned char* __restrict__ hinB,  // [N][256] bytes (fp16 rows)
    const int* __restrict__ rs,              // [N+1]
    const unsigned int* __restrict__ csr,    // [E] packed (src | f16w<<16)
    const _Float16* __restrict__ Wt,         // [128,128] fp16 n-major
    const float* __restrict__ bias,          // [128] fp32
    _Float16* __restrict__ hout,             // [N,128] fp16 (unused if DEC)
    const _Float16* __restrict__ decWt,      // [64,128] fp16 n-major (DEC only)
    const float* __restrict__ dec_b,         // [64] (DEC only)
    float* __restrict__ decout)              // [N,64] fp32 (DEC only)
{
    __shared__ _Float16 Alds[16][136];

    const int t    = threadIdx.x;
    const int wv   = __builtin_amdgcn_readfirstlane(t >> 6);   // 0..3
    const int lane = t & 63;
    const int grp  = lane >> 4;
    const int li   = lane & 15;
    const int base = blockIdx.x * 16;

    for (int i = 0; i < 4; ++i) {
        const int r   = wv * 4 + i;
        const int wid = base + r;
        const int e0  = rs[wid];
        const int e1  = rs[wid + 1];

        float acc[8];
        #pragma unroll
        for (int q = 0; q < 8; ++q) acc[q] = 0.f;

        for (int sb = e0; sb < e1; sb += 64) {
            const int nrem = min(64, e1 - sb);
            unsigned int vp = csr[sb + (lane < nrem ? lane : 0)];
            const int nfg = nrem >> 2;
            int g = 0;
            for (; g + 4 <= nfg; g += 4) {
                unsigned int ps[4]; uint4 v[4];
                #pragma unroll
                for (int q = 0; q < 4; ++q) ps[q] = __shfl(vp, 4 * (g + q) + grp, 64);
                #pragma unroll
                for (int q = 0; q < 4; ++q)
                    v[q] = *(const uint4*)(hinB + ((ps[q] & 0x3FFFu) << 8) + (li << 4));
                #pragma unroll
                for (int q = 0; q < 4; ++q) EDGE_ACC(ps[q], v[q]);
            }
            for (; g < nfg; ++g) {
                unsigned int ps = __shfl(vp, 4 * g + grp, 64);
                uint4 v = *(const uint4*)(hinB + ((ps & 0x3FFFu) << 8) + (li << 4));
                EDGE_ACC(ps, v);
            }
            if (nrem & 3) {
                unsigned int ps = __shfl(vp, 4 * g + grp, 64);
                if (4 * g + grp >= nrem) ps &= 0x3FFFu;   // weight := +0.0
                uint4 v = *(const uint4*)(hinB + ((ps & 0x3FFFu) << 8) + (li << 4));
                EDGE_ACC(ps, v);
            }
        }

        #pragma unroll
        for (int q = 0; q < 8; ++q) {
            float s = acc[q];
            s += __shfl_xor(s, 16, 64);
            s += __shfl_xor(s, 32, 64);
            acc[q] = s;
        }

        if (grp == 0) {
            _Float16 hv[8];
            #pragma unroll
            for (int q = 0; q < 8; ++q) hv[q] = (_Float16)acc[q];
            *(uint4*)(&Alds[r][li * 8]) = *(uint4*)hv;
        }
    }
    __syncthreads();

    // MFMA: wave wv computes col-tiles wv and wv+4
    const int m  = li;
    const int kg = grp;
    float tv[2][4];
    #pragma unroll
    for (int q = 0; q < 2; ++q) {
        const int ct = wv + q * 4;
        f32x4 macc = (f32x4){0.f, 0.f, 0.f, 0.f};
        #pragma unroll
        for (int ks = 0; ks < 4; ++ks) {
            half8 a  = *(const half8*)(&Alds[m][kg * 8 + ks * 32]);
            half8 bb = *(const half8*)(Wt + (size_t)(ct * 16 + m) * 128 + ks * 32 + kg * 8);
            macc = __builtin_amdgcn_mfma_f32_16x16x32_f16(a, bb, macc, 0, 0, 0);
        }
        const float bv = bias[ct * 16 + m];
        #pragma unroll
        for (int r = 0; r < 4; ++r) tv[q][r] = tanhf(macc[r] + bv);
    }

    if (!DEC) {
        #pragma unroll
        for (int q = 0; q < 2; ++q) {
            const int col = (wv + q * 4) * 16 + m;
            #pragma unroll
            for (int r = 0; r < 4; ++r)
                hout[(size_t)(base + kg * 4 + r) * 128 + col] = (_Float16)tv[q][r];
        }
    } else {
        __syncthreads();   // all Alds reads done; reuse tile for tanh'd h
        #pragma unroll
        for (int q = 0; q < 2; ++q) {
            const int col = (wv + q * 4) * 16 + m;
            #pragma unroll
            for (int r = 0; r < 4; ++r) Alds[kg * 4 + r][col] = (_Float16)tv[q][r];
        }
        __syncthreads();
        // decoder: 64 cols, wave wv does col-tile wv
        f32x4 dacc = (f32x4){0.f, 0.f, 0.f, 0.f};
        #pragma unroll
        for (int ks = 0; ks < 4; ++ks) {
            half8 a  = *(const half8*)(&Alds[m][kg * 8 + ks * 32]);
            half8 bb = *(const half8*)(decWt + (size_t)(wv * 16 + m) * 128 + ks * 32 + kg * 8);
            dacc = __builtin_amdgcn_mfma_f32_16x16x32_f16(a, bb, dacc, 0, 0, 0);
        }
        const float dbv = dec_b[wv * 16 + m];
        #pragma unroll
        for (int r = 0; r < 4; ++r)
            decout[(size_t)(base + kg * 4 + r) * 64 + wv * 16 + m] = dacc[r] + dbv;
    }
}

// ---------------- launch ----------------
extern "C" void kernel_launch(void* const* d_in, const int* in_sizes, int n_in,
                              void* d_out, int out_size, void* d_ws, size_t ws_size,
                              hipStream_t stream)
{
    const float* x      = (const float*)d_in[0];
    const int*   ei     = (const int*)  d_in[1];
    const float* ew     = (const float*)d_in[2];
    const float* enc_W  = (const float*)d_in[3];
    const float* enc_b  = (const float*)d_in[4];
    const float* conv_W = (const float*)d_in[5];
    const float* conv_b = (const float*)d_in[6];
    const float* dec_W  = (const float*)d_in[7];
    const float* dec_b  = (const float*)d_in[8];
    float* out = (float*)d_out;

    const int N = NNODES, E = NEDGES, H = HDIM;

    // workspace layout
    _Float16*       h      = (_Float16*)d_ws;                     // [N,128]  2.56MB
    _Float16*       h2     = h + (size_t)N * H;                   // [N,128]  2.56MB
    _Float16*       wt_all = h2 + (size_t)N * H;                  // 81920    160KB
    unsigned int*   csr    = (unsigned int*)(wt_all + 5 * 16384); // [E]      2.56MB
    unsigned short* counts = (unsigned short*)(csr + E);          // [NB][N]  4MB
    int*            total  = (int*)(counts + (size_t)NB * N);     // [N]
    int*            rs     = total + N;                           // [N+1]
    int*            cur    = rs + (N + 1);                        // [N]

    const int* src = ei;
    const int* dst = ei + E;

    prep_kernel<<<6, 256, 0, stream>>>(enc_W, conv_W, dec_W, wt_all, total);

    // fused: hist (200 blocks) + encoder (157 blocks)
    enc_hist_kernel<<<NB + ENCB, 1024, 0, stream>>>(dst, counts, total, x, wt_all, enc_b, h);

    scan_kernel<<<1, 1024, 0, stream>>>(total, rs, cur);
    passB_claim<<<NB, 1024, 0, stream>>>(src, dst, ew, counts, cur, csr);

    // conv layers (linearity reorder): h_{l+1} = tanh((sum w*h_l[src]) @ W_l + b_l)
    conv_fused<false><<<N / 16, 256, 0, stream>>>((const unsigned char*)h, rs, csr,
                                                  wt_all + 1 * 16384, conv_b + 0 * H,
                                                  h2, nullptr, nullptr, nullptr);
    conv_fused<false><<<N / 16, 256, 0, stream>>>((const unsigned char*)h2, rs, csr,
                                                  wt_all + 2 * 16384, conv_b + 1 * H,
                                                  h, nullptr, nullptr, nullptr);
    conv_fused<true><<<N / 16, 256, 0, stream>>>((const unsigned char*)h, rs, csr,
                                                 wt_all + 3 * 16384, conv_b + 2 * H,
                                                 h2, wt_all + 4 * 16384, dec_b, out);
}

// Round 17
// 120.862 us; speedup vs baseline: 1.7672x; 1.0676x over previous
//
#include <hip/hip_runtime.h>
#include <hip/hip_bf16.h>
#include <hip/hip_fp16.h>

// GCN round 17: R14 base + conv gather unrolled 8-wide (32 edges/iter, 8
// dwordx4 in flight per wave) for memory-level parallelism. No occupancy pin.
// 7 launches: prep, enc+hist, scan, passB(claim), conv1, conv2, conv3+dec.

#define NNODES 10000
#define NEDGES 640000
#define HDIM   128
#define CDIM   64
#define NLAYER 3
#define NB     200
#define CHUNK  (NEDGES / NB)
#define ENCB   157               // encoder blocks in fused kernel

typedef _Float16 half8 __attribute__((ext_vector_type(8)));
typedef float    f32x4 __attribute__((ext_vector_type(4)));

// ---------------- prep: weights -> transposed fp16 [n][k]; zero total ----------------
__global__ __launch_bounds__(256) void prep_kernel(
    const float* __restrict__ enc_W,
    const float* __restrict__ conv_W,
    const float* __restrict__ dec_W,
    _Float16* __restrict__ wt_all,     // enc[16384] conv[3*16384] dec[8192]
    int* __restrict__ total)
{
    const int b = blockIdx.x, t = threadIdx.x;
    if (b == 5) {
        for (int i = t; i < NNODES; i += 256) total[i] = 0;
        return;
    }
    const float* W; _Float16* Wt; int NC, tot;
    if (b == 0)      { W = enc_W;                  Wt = wt_all;             NC = 128; tot = 16384; }
    else if (b <= 3) { W = conv_W + (b - 1) * 16384; Wt = wt_all + b * 16384; NC = 128; tot = 16384; }
    else             { W = dec_W;                  Wt = wt_all + 4 * 16384; NC = 64;  tot = 8192; }
    for (int idx = t; idx < tot; idx += 256) {
        int n = idx >> 7, k = idx & 127;
        Wt[idx] = (_Float16)W[k * NC + n];
    }
}

// ---- encoder tile (16 rows), executed by a 256-thread subgroup ----
__device__ __forceinline__ void enc_tile(int tile, int tid,
    const float* __restrict__ A, const _Float16* __restrict__ Wt,
    const float* __restrict__ bias, _Float16* __restrict__ outv)
{
    const int wave = tid >> 6;
    const int lane = tid & 63;
    const int base = tile * 16;
    const int m  = lane & 15;
    const int kg = lane >> 4;
    const int row = base + m;

    f32x4 acc[2];
    acc[0] = (f32x4){0.f, 0.f, 0.f, 0.f};
    acc[1] = (f32x4){0.f, 0.f, 0.f, 0.f};

    #pragma unroll
    for (int ks = 0; ks < 4; ++ks) {
        half8 a;
        const float* ap = A + (size_t)row * 128 + kg * 8 + ks * 32;
        float4 u0 = *(const float4*)(ap);
        float4 u1 = *(const float4*)(ap + 4);
        a[0] = (_Float16)u0.x; a[1] = (_Float16)u0.y;
        a[2] = (_Float16)u0.z; a[3] = (_Float16)u0.w;
        a[4] = (_Float16)u1.x; a[5] = (_Float16)u1.y;
        a[6] = (_Float16)u1.z; a[7] = (_Float16)u1.w;
        #pragma unroll
        for (int q = 0; q < 2; ++q) {
            const int nt = wave + q * 4;
            half8 b = *(const half8*)(Wt + (size_t)(nt * 16 + m) * 128 + ks * 32 + kg * 8);
            acc[q] = __builtin_amdgcn_mfma_f32_16x16x32_f16(a, b, acc[q], 0, 0, 0);
        }
    }

    #pragma unroll
    for (int q = 0; q < 2; ++q) {
        const int col = (wave + q * 4) * 16 + m;
        float bv = bias[col];
        #pragma unroll
        for (int r = 0; r < 4; ++r) {
            int orow = base + kg * 4 + r;
            outv[(size_t)orow * 128 + col] = (_Float16)tanhf(acc[q][r] + bv);
        }
    }
}

// ---------------- fused: hist (blocks 0..NB-1) + encoder (blocks NB..) ----------------
__global__ __launch_bounds__(1024) void enc_hist_kernel(
    const int* __restrict__ dst,
    unsigned short* __restrict__ counts,
    int* __restrict__ total,
    const float* __restrict__ x,
    const _Float16* __restrict__ encWt,
    const float* __restrict__ enc_b,
    _Float16* __restrict__ h)
{
    __shared__ int hist[NNODES];
    const int b = blockIdx.x, t = threadIdx.x;

    if (b >= NB) {
        int tile = (b - NB) * 4 + (t >> 8);
        if (tile < NNODES / 16)
            enc_tile(tile, t & 255, x, encWt, enc_b, h);
        return;
    }

    for (int i = t; i < NNODES; i += 1024) hist[i] = 0;
    __syncthreads();
    const int e0 = b * CHUNK, e1 = e0 + CHUNK;
    for (int e = e0 + t; e < e1; e += 1024) atomicAdd(&hist[dst[e]], 1);
    __syncthreads();
    for (int i = t; i < NNODES; i += 1024) {
        int c = hist[i];
        counts[b * NNODES + i] = (unsigned short)c;
        if (c) atomicAdd(&total[i], c);
    }
}

// ---------------- scan: rs = exclusive_scan(total); cur = rs ----------------
__global__ __launch_bounds__(1024) void scan_kernel(const int* __restrict__ total,
                                                    int* __restrict__ rs,
                                                    int* __restrict__ cur)
{
    __shared__ int part[1024];
    const int t = threadIdx.x;
    const int per = (NNODES + 1023) / 1024;
    const int begin = t * per;
    int s = 0;
    for (int j = 0; j < per; ++j) {
        int i = begin + j;
        if (i < NNODES) s += total[i];
    }
    part[t] = s;
    __syncthreads();
    for (int off = 1; off < 1024; off <<= 1) {
        int v = (t >= off) ? part[t - off] : 0;
        __syncthreads();
        part[t] += v;
        __syncthreads();
    }
    int excl = part[t] - s;
    for (int j = 0; j < per; ++j) {
        int i = begin + j;
        if (i < NNODES) {
            rs[i]  = excl;
            cur[i] = excl;
            excl += total[i];
        }
    }
    if (t == 1023) rs[NNODES] = part[1023];
}

// ---------------- passB: load counts row, claim ranges, LDS-cursor scatter ----------------
__global__ __launch_bounds__(1024) void passB_claim(const int* __restrict__ src,
                                                    const int* __restrict__ dst,
                                                    const float* __restrict__ ew,
                                                    const unsigned short* __restrict__ counts,
                                                    int* __restrict__ cur,
                                                    unsigned int* __restrict__ csr)
{
    __shared__ int hist[NNODES];
    const int b = blockIdx.x, t = threadIdx.x;
    for (int i = t; i < NNODES; i += 1024) {
        int c = counts[b * NNODES + i];
        hist[i] = c ? atomicAdd(&cur[i], c) : 0;
    }
    __syncthreads();
    const int e0 = b * CHUNK, e1 = e0 + CHUNK;
    for (int e = e0 + t; e < e1; e += 1024) {
        int d = dst[e];
        int p = atomicAdd(&hist[d], 1);
        unsigned int pk = (unsigned int)src[e]
                        | ((unsigned int)__half_as_ushort(__float2half_rn(ew[e])) << 16);
        csr[p] = pk;
    }
}

// ---------------- fused conv layer: 512 thr, 8 waves x 2 nodes, 8-wide MLP ----------------
#define EDGE_ACC(pk, vv)                                                 \
    do {                                                                 \
        __half wh; *(unsigned short*)&wh = (unsigned short)((pk) >> 16); \
        float w = __half2float(wh);                                      \
        half8 hv = *(const half8*)&(vv);                                 \
        _Pragma("unroll")                                                \
        for (int j = 0; j < 8; ++j)                                      \
            acc[j] = fmaf((float)hv[j], w, acc[j]);                      \
    } while (0)

template<bool DEC>
__global__ __launch_bounds__(512) void conv_fused(
    const unsigned char* __restrict__ hinB,  // [N][256] bytes (fp16 rows)
    const int* __restrict__ rs,              // [N+1]
    const unsigned int* __restrict__ csr,    // [E] packed (src | f16w<<16)
    const _Float16* __restrict__ Wt,         // [128,128] fp16 n-major
    const float* __restrict__ bias,          // [128] fp32
    _Float16* __restrict__ hout,             // [N,128] fp16 (unused if DEC)
    const _Float16* __restrict__ decWt,      // [64,128] fp16 n-major (DEC only)
    const float* __restrict__ dec_b,         // [64] (DEC only)
    float* __restrict__ decout)              // [N,64] fp32 (DEC only)
{
    __shared__ _Float16 Alds[16][136];

    const int t    = threadIdx.x;
    const int wv   = __builtin_amdgcn_readfirstlane(t >> 6);   // 0..7
    const int lane = t & 63;
    const int grp  = lane >> 4;
    const int li   = lane & 15;
    const int base = blockIdx.x * 16;

    #pragma unroll
    for (int i = 0; i < 2; ++i) {
        const int r   = wv * 2 + i;
        const int wid = base + r;
        const int e0  = rs[wid];
        const int e1  = rs[wid + 1];

        float acc[8];
        #pragma unroll
        for (int q = 0; q < 8; ++q) acc[q] = 0.f;

        for (int sb = e0; sb < e1; sb += 64) {
            const int nrem = min(64, e1 - sb);
            unsigned int vp = csr[sb + (lane < nrem ? lane : 0)];
            const int nfg = nrem >> 2;
            int g = 0;
            // 8 groups (32 edges) per iteration: 8 dwordx4 gathers in flight
            for (; g + 8 <= nfg; g += 8) {
                unsigned int ps[8]; uint4 v[8];
                #pragma unroll
                for (int q = 0; q < 8; ++q) ps[q] = __shfl(vp, 4 * (g + q) + grp, 64);
                #pragma unroll
                for (int q = 0; q < 8; ++q)
                    v[q] = *(const uint4*)(hinB + ((ps[q] & 0x3FFFu) << 8) + (li << 4));
                #pragma unroll
                for (int q = 0; q < 8; ++q) EDGE_ACC(ps[q], v[q]);
            }
            for (; g + 4 <= nfg; g += 4) {
                unsigned int ps[4]; uint4 v[4];
                #pragma unroll
                for (int q = 0; q < 4; ++q) ps[q] = __shfl(vp, 4 * (g + q) + grp, 64);
                #pragma unroll
                for (int q = 0; q < 4; ++q)
                    v[q] = *(const uint4*)(hinB + ((ps[q] & 0x3FFFu) << 8) + (li << 4));
                #pragma unroll
                for (int q = 0; q < 4; ++q) EDGE_ACC(ps[q], v[q]);
            }
            for (; g < nfg; ++g) {
                unsigned int ps = __shfl(vp, 4 * g + grp, 64);
                uint4 v = *(const uint4*)(hinB + ((ps & 0x3FFFu) << 8) + (li << 4));
                EDGE_ACC(ps, v);
            }
            if (nrem & 3) {
                unsigned int ps = __shfl(vp, 4 * g + grp, 64);
                if (4 * g + grp >= nrem) ps &= 0x3FFFu;   // weight := +0.0
                uint4 v = *(const uint4*)(hinB + ((ps & 0x3FFFu) << 8) + (li << 4));
                EDGE_ACC(ps, v);
            }
        }

        #pragma unroll
        for (int q = 0; q < 8; ++q) {
            float s = acc[q];
            s += __shfl_xor(s, 16, 64);
            s += __shfl_xor(s, 32, 64);
            acc[q] = s;
        }

        if (grp == 0) {
            _Float16 hv[8];
            #pragma unroll
            for (int q = 0; q < 8; ++q) hv[q] = (_Float16)acc[q];
            *(uint4*)(&Alds[r][li * 8]) = *(uint4*)hv;
        }
    }
    __syncthreads();

    const int m  = li;
    const int kg = grp;
    f32x4 macc = (f32x4){0.f, 0.f, 0.f, 0.f};
    #pragma unroll
    for (int ks = 0; ks < 4; ++ks) {
        half8 a  = *(const half8*)(&Alds[m][kg * 8 + ks * 32]);
        half8 bb = *(const half8*)(Wt + (size_t)(wv * 16 + m) * 128 + ks * 32 + kg * 8);
        macc = __builtin_amdgcn_mfma_f32_16x16x32_f16(a, bb, macc, 0, 0, 0);
    }

    const int col = wv * 16 + m;
    const float bv = bias[col];
    float tv[4];
    #pragma unroll
    for (int r = 0; r < 4; ++r) tv[r] = tanhf(macc[r] + bv);

    if (!DEC) {
        #pragma unroll
        for (int r = 0; r < 4; ++r)
            hout[(size_t)(base + kg * 4 + r) * 128 + col] = (_Float16)tv[r];
    } else {
        __syncthreads();   // Alds reads complete; reuse tile for tanh'd h
        #pragma unroll
        for (int r = 0; r < 4; ++r) Alds[kg * 4 + r][col] = (_Float16)tv[r];
        __syncthreads();
        if (wv < 4) {
            f32x4 dacc = (f32x4){0.f, 0.f, 0.f, 0.f};
            #pragma unroll
            for (int ks = 0; ks < 4; ++ks) {
                half8 a  = *(const half8*)(&Alds[m][kg * 8 + ks * 32]);
                half8 bb = *(const half8*)(decWt + (size_t)(wv * 16 + m) * 128 + ks * 32 + kg * 8);
                dacc = __builtin_amdgcn_mfma_f32_16x16x32_f16(a, bb, dacc, 0, 0, 0);
            }
            const float dbv = dec_b[wv * 16 + m];
            #pragma unroll
            for (int r = 0; r < 4; ++r)
                decout[(size_t)(base + kg * 4 + r) * 64 + wv * 16 + m] = dacc[r] + dbv;
        }
    }
}

// ---------------- launch ----------------
extern "C" void kernel_launch(void* const* d_in, const int* in_sizes, int n_in,
                              void* d_out, int out_size, void* d_ws, size_t ws_size,
                              hipStream_t stream)
{
    const float* x      = (const float*)d_in[0];
    const int*   ei     = (const int*)  d_in[1];
    const float* ew     = (const float*)d_in[2];
    const float* enc_W  = (const float*)d_in[3];
    const float* enc_b  = (const float*)d_in[4];
    const float* conv_W = (const float*)d_in[5];
    const float* conv_b = (const float*)d_in[6];
    const float* dec_W  = (const float*)d_in[7];
    const float* dec_b  = (const float*)d_in[8];
    float* out = (float*)d_out;

    const int N = NNODES, E = NEDGES, H = HDIM;

    // workspace layout
    _Float16*       h      = (_Float16*)d_ws;                     // [N,128]  2.56MB
    _Float16*       h2     = h + (size_t)N * H;                   // [N,128]  2.56MB
    _Float16*       wt_all = h2 + (size_t)N * H;                  // 81920    160KB
    unsigned int*   csr    = (unsigned int*)(wt_all + 5 * 16384); // [E]      2.56MB
    unsigned short* counts = (unsigned short*)(csr + E);          // [NB][N]  4MB
    int*            total  = (int*)(counts + (size_t)NB * N);     // [N]
    int*            rs     = total + N;                           // [N+1]
    int*            cur    = rs + (N + 1);                        // [N]

    const int* src = ei;
    const int* dst = ei + E;

    prep_kernel<<<6, 256, 0, stream>>>(enc_W, conv_W, dec_W, wt_all, total);

    // fused: hist (200 blocks) + encoder (157 blocks)
    enc_hist_kernel<<<NB + ENCB, 1024, 0, stream>>>(dst, counts, total, x, wt_all, enc_b, h);

    scan_kernel<<<1, 1024, 0, stream>>>(total, rs, cur);
    passB_claim<<<NB, 1024, 0, stream>>>(src, dst, ew, counts, cur, csr);

    // conv layers (linearity reorder): h_{l+1} = tanh((sum w*h_l[src]) @ W_l + b_l)
    conv_fused<false><<<N / 16, 512, 0, stream>>>((const unsigned char*)h, rs, csr,
                                                  wt_all + 1 * 16384, conv_b + 0 * H,
                                                  h2, nullptr, nullptr, nullptr);
    conv_fused<false><<<N / 16, 512, 0, stream>>>((const unsigned char*)h2, rs, csr,
                                                  wt_all + 2 * 16384, conv_b + 1 * H,
                                                  h, nullptr, nullptr, nullptr);
    conv_fused<true><<<N / 16, 512, 0, stream>>>((const unsigned char*)h, rs, csr,
                                                 wt_all + 3 * 16384, conv_b + 2 * H,
                                                 h2, wt_all + 4 * 16384, dec_b, out);
}